// Round 11
// baseline (1338.759 us; speedup 1.0000x reference)
//
#include <hip/hip_runtime.h>
#include <hip/hip_bf16.h>
#include <cstdint>
#include <cstddef>

#define HEADS 16
#define HD 64
#define NT 49
#define NTOK 3136          // NT*HD
#define MROWS 100352       // 2048*49
#define KDIM 1024

typedef __attribute__((ext_vector_type(4))) float f32x4;
typedef __attribute__((ext_vector_type(8))) short bf16x8;
typedef __attribute__((ext_vector_type(4))) unsigned short u16x4;

__device__ __forceinline__ unsigned short f2b(float f) {
  __hip_bfloat16 h = __float2bfloat16(f);
  return *reinterpret_cast<unsigned short*>(&h);
}
__device__ __forceinline__ float b2f(unsigned short u) {
  union { unsigned int i; float f; } c; c.i = ((unsigned int)u) << 16; return c.f;
}

__device__ __forceinline__ void gload16(const unsigned short* g, void* l) {
  __builtin_amdgcn_global_load_lds(
      (const __attribute__((address_space(1))) void*)g,
      (__attribute__((address_space(3))) void*)l, 16, 0, 0);
}

__device__ __forceinline__ void bar() {
  asm volatile("" ::: "memory");
  __builtin_amdgcn_s_barrier();
  asm volatile("" ::: "memory");
}

// ---------------- fp32 -> bf16 convert ----------------
__global__ void cvt_f32_bf16(const float* __restrict__ s,
                             unsigned short* __restrict__ d, long n4) {
  long stride = (long)gridDim.x * blockDim.x;
  for (long i = blockIdx.x * (long)blockDim.x + threadIdx.x; i < n4; i += stride) {
    f32x4 v = reinterpret_cast<const f32x4*>(s)[i];
    u16x4 o;
    o.x = f2b(v.x); o.y = f2b(v.y); o.z = f2b(v.z); o.w = f2b(v.w);
    reinterpret_cast<u16x4*>(d)[i] = o;
  }
}

// ---------------- fused (window mask + rel-pos bias) logit table ----------------
// BM[wm][h][a][b] for a<49, b<64; b>=49 baked to -1e30. 64*16*49*64*4B = 12.8 MB.
__global__ void build_bm(const float* __restrict__ mask,
                         const float* __restrict__ bias_table,
                         float* __restrict__ bm) {
  const int wm = blockIdx.x >> 4, h = blockIdx.x & 15;
  const float* mrow = mask + (size_t)wm * (NT * NT);
  float* dst = bm + ((size_t)wm * HEADS + h) * (NT * 64);
  for (int idx = threadIdx.x; idx < NT * 64; idx += 256) {
    const int a = idx >> 6, b = idx & 63;
    float v = -1e30f;
    if (b < NT) {
      const int ia = a / 7, ja = a - ia * 7;
      const int ib = b / 7, jb = b - ib * 7;
      v = mrow[a * NT + b] +
          bias_table[((ia - ib + 6) * 13 + (ja - jb + 6)) * HEADS + h];
    }
    dst[idx] = v;
  }
}

// ---------------- bf16 B^T GEMM, 256x128 tile, BK=32, 4-wave (128x64/wave) ----------------
// (round-10 structure — measured best: ~702 us QKV, MfmaUtil ~41)
template<int EPI>
__global__ __launch_bounds__(256, 2)
void gemm_bt(const unsigned short* __restrict__ A,
             const unsigned short* __restrict__ B,
             const float* __restrict__ bias,
             void* __restrict__ Cout,
             const int nTilesN) {
  __shared__ __align__(16) unsigned short lds[2 * 12288]; // 48 KiB

  const int nwg = gridDim.x;
  const int bid = blockIdx.x;
  const int cpx = nwg >> 3;                       // nwg % 8 == 0 (9408 / 3136)
  const int swz = (bid & 7) * cpx + (bid >> 3);   // XCD-contiguous chunks (T1)
  const int mt = swz / nTilesN;
  const int nt = swz - mt * nTilesN;
  const long mBase = (long)mt * 256;
  const int nBase = nt * 128;

  const int tid = threadIdx.x;
  const int lane = tid & 63;
  const int wid = tid >> 6;
  const int wr = wid >> 1;        // 0..1  (M half: 128 rows)
  const int wc = wid & 1;         // 0..1  (N half: 64 cols)
  const int lr = lane & 15;
  const int kg = lane >> 4;       // 0..3

  // staging: thread covers rows (tid>>2)+64s, slot (tid&3); src col pre-swizzled
  const int srow = tid >> 2;                              // 0..63
  const int c8 = (((tid & 3) ^ ((tid >> 3) & 3)) << 3);   // shorts
  const unsigned short* aSrc = A + (size_t)(mBase + srow) * KDIM + c8;
  const unsigned short* bSrc = B + (size_t)(nBase + srow) * KDIM + c8;
  char* ldsB = (char*)lds;

  f32x4 acc[8][4] = {};

  // fragment read offsets (shorts), swizzled: row*32 + (kg ^ ((row>>1)&3))*8
  int aOff[8], bOff[4];
#pragma unroll
  for (int m = 0; m < 8; ++m) {
    const int row = wr * 128 + m * 16 + lr;
    aOff[m] = row * 32 + ((kg ^ ((row >> 1) & 3)) << 3);
  }
#pragma unroll
  for (int n = 0; n < 4; ++n) {
    const int row = wc * 64 + n * 16 + lr;
    bOff[n] = row * 32 + ((kg ^ ((row >> 1) & 3)) << 3);
  }

  // A: 4 segments of 64 rows (16 KB), B: 2 segments (8 KB); 6 gloads/thread
#define STAGE(buf, kt) do {                                         \
    char* dst = ldsB + (buf) * 24576 + tid * 16;                    \
    _Pragma("unroll")                                               \
    for (int s = 0; s < 4; ++s)                                     \
      gload16(aSrc + (size_t)s * 64 * KDIM + (kt) * 32, dst + s * 4096); \
    _Pragma("unroll")                                               \
    for (int s = 0; s < 2; ++s)                                     \
      gload16(bSrc + (size_t)s * 64 * KDIM + (kt) * 32,             \
              dst + 16384 + s * 4096);                              \
  } while (0)

  // prologue: tiles 0 and 1 in flight; wait tile 0 only (6 per tile per thread)
  STAGE(0, 0);
  STAGE(1, 1);
  asm volatile("s_waitcnt vmcnt(6)" ::: "memory");
  __builtin_amdgcn_sched_barrier(0);
  bar();

  for (int kt = 0; kt < KDIM / 32; ++kt) {
    const int cb = kt & 1;
    const unsigned short* As = lds + cb * 12288;
    const unsigned short* Bs = As + 8192;

    bf16x8 af[8], bfv[4];
#pragma unroll
    for (int m = 0; m < 8; ++m)
      af[m] = *reinterpret_cast<const bf16x8*>(As + aOff[m]);
#pragma unroll
    for (int n = 0; n < 4; ++n)
      bfv[n] = *reinterpret_cast<const bf16x8*>(Bs + bOff[n]);

    __builtin_amdgcn_s_setprio(1);
#pragma unroll
    for (int m = 0; m < 8; ++m)
#pragma unroll
      for (int n = 0; n < 4; ++n)
        acc[m][n] = __builtin_amdgcn_mfma_f32_16x16x32_bf16(
            af[m], bfv[n], acc[m][n], 0, 0, 0);
    __builtin_amdgcn_s_setprio(0);
    bar();   // all waves done reading buf[cb]

    if (kt < KDIM / 32 - 2) {
      STAGE(cb, kt + 2);
      asm volatile("s_waitcnt vmcnt(6)" ::: "memory");  // tile kt+1 landed
      __builtin_amdgcn_sched_barrier(0);
      bar();
    } else if (kt == KDIM / 32 - 2) {
      asm volatile("s_waitcnt vmcnt(0)" ::: "memory");  // drain last tile
      __builtin_amdgcn_sched_barrier(0);
      bar();
    }
  }
#undef STAGE

  if (EPI == 0) {
    unsigned short* qkvbuf = (unsigned short*)Cout;
#pragma unroll
    for (int m = 0; m < 8; ++m) {
      const int row0 = wr * 128 + m * 16 + kg * 4;
#pragma unroll
      for (int n = 0; n < 4; ++n) {
        const int col = nBase + wc * 64 + n * 16 + lr;
        const int which = col >> 10;
        const int head = (col >> 6) & 15;
        const int d = col & 63;
        const float bv = bias[col];
#pragma unroll
        for (int r = 0; r < 4; ++r) {
          const int gm = (int)mBase + row0 + r;
          const int w = gm / NT;
          const int t = gm - w * NT;
          float v = acc[m][n][r] + bv;
          if (which == 0) v *= 0.125f;
          qkvbuf[(((size_t)w * 3 + which) * HEADS + head) * NTOK + t * HD + d] =
              f2b(v);
        }
      }
    }
  } else {
    float* out = (float*)Cout;
#pragma unroll
    for (int m = 0; m < 8; ++m) {
      const int row0 = wr * 128 + m * 16 + kg * 4;
#pragma unroll
      for (int n = 0; n < 4; ++n) {
        const int col = nBase + wc * 64 + n * 16 + lr;
        const float bv = bias[col];
#pragma unroll
        for (int r = 0; r < 4; ++r) {
          const int gm = (int)mBase + row0 + r;
          out[(size_t)gm * KDIM + col] = acc[m][n][r] + bv;
        }
      }
    }
  }
}

// ---------------- window attention: 4 waves per (window, head) ----------------
// Round-9 structure + coalesced O epilogue: after PV, O goes through the
// (now dead) VldsT buffer and is stored as 392 x 16B chunks — 128B lines,
// replacing 16 scalar 2B global stores per thread.
#define PSTR 72   // P LDS stride (elements), 16B-aligned rows
#define VTSTR 72  // V^T LDS stride (elements): 8 data slots of 16B + 1 pad

__global__ __launch_bounds__(256, 8)
void attn_mfma(const unsigned short* __restrict__ qkv,
               const float* __restrict__ bm,
               unsigned short* __restrict__ aout) {
  const int blk = blockIdx.x;
  const int w = blk >> 4;
  const int h = blk & 15;
  const int tid = threadIdx.x;
  const int lane = tid & 63;
  const int wv = tid >> 6;        // 0..3: Q-row quarter
  const int lr = lane & 15;
  const int kg = lane >> 4;

  __shared__ __align__(16) unsigned short Plds[64 * PSTR];
  __shared__ __align__(16) unsigned short VldsT[64 * VTSTR];

  const unsigned short* qp = qkv + (((size_t)w * 3 + 0) * HEADS + h) * NTOK;
  const unsigned short* kp = qp + (size_t)HEADS * NTOK;
  const unsigned short* vp = qp + (size_t)2 * HEADS * NTOK;
  const float* bmrow = bm + (((size_t)(w & 63) * HEADS + h) * (NT * 64));

  // ---- issue V global loads FIRST (load-early / write-late) ----
  const int t0 = tid >> 3, c0 = (tid & 7) * 8;          // chunk tid: rows 0..31
  bf16x8 vreg0 = *reinterpret_cast<const bf16x8*>(vp + t0 * HD + c0);
  const int idx1 = tid + 256;                           // chunk tid+256
  const int t1 = idx1 >> 3, c1 = (idx1 & 7) * 8;        // rows 32..63
  bf16x8 vreg1 = {};
  if (t1 < NT)
    vreg1 = *reinterpret_cast<const bf16x8*>(vp + t1 * HD + c1);

  // ---- bm preload (issued second; consumed after sync) ----
  const int a0 = wv * 16 + kg * 4;          // this wave's 4 a-rows start
  f32x4 acc[4];
#pragma unroll
  for (int r = 0; r < 4; ++r) {
    const int a = a0 + r;
    const int ar = (a > 48) ? 48 : a;
#pragma unroll
    for (int n = 0; n < 4; ++n)
      acc[n][r] = bmrow[ar * 64 + n * 16 + lr];
  }

  // ---- V^T transpose-write into LDS (waits on vreg only here) ----
  {
    const int ts0 = t0 >> 3, t70 = t0 & 7;
#pragma unroll
    for (int ii = 0; ii < 8; ++ii) {
      const int d = c0 + ii;
      VldsT[d * VTSTR + (((ts0 ^ (d & 7)) << 3) + t70)] =
          ((const unsigned short*)&vreg0)[ii];
    }
  }
  if (t1 < NT) {
    const int ts1 = t1 >> 3, t71 = t1 & 7;
#pragma unroll
    for (int ii = 0; ii < 8; ++ii) {
      const int d = c1 + ii;
      VldsT[d * VTSTR + (((ts1 ^ (d & 7)) << 3) + t71)] =
          ((const unsigned short*)&vreg1)[ii];
    }
  }
  // zero pad cols t=49..63 for all 64 d-rows (swizzled)
#pragma unroll
  for (int i = 0; i < 4; ++i) {
    const int idx = i * 256 + tid;          // 64*15 = 960
    if (idx < 960) {
      const int d = idx / 15, t = 49 + idx - d * 15;
      VldsT[d * VTSTR + ((((t >> 3) ^ (d & 7)) << 3) + (t & 7))] = 0;
    }
  }
  __syncthreads();   // V^T visible to all 4 waves before PV

  // ---- QK^T: direct global fragment loads (1 Q-frag, 4 K-frags per ks) ----
  int qrow = wv * 16 + lr; if (qrow > 48) qrow = 48;
#pragma unroll
  for (int ks = 0; ks < 2; ++ks) {
    bf16x8 af = *reinterpret_cast<const bf16x8*>(qp + qrow * HD + ks * 32 + kg * 8);
#pragma unroll
    for (int n = 0; n < 4; ++n) {
      int row = n * 16 + lr; if (row > 48) row = 48;
      bf16x8 bfr = *reinterpret_cast<const bf16x8*>(kp + row * HD + ks * 32 + kg * 8);
      acc[n] = __builtin_amdgcn_mfma_f32_16x16x32_bf16(af, bfr, acc[n], 0, 0, 0);
    }
  }

  // ---- in-register softmax: row a lives in the 16 lanes sharing kg ----
#pragma unroll
  for (int r = 0; r < 4; ++r) {
    float mx = fmaxf(fmaxf(acc[0][r], acc[1][r]),
                     fmaxf(acc[2][r], acc[3][r]));
    mx = fmaxf(mx, __shfl_xor(mx, 1));
    mx = fmaxf(mx, __shfl_xor(mx, 2));
    mx = fmaxf(mx, __shfl_xor(mx, 4));
    mx = fmaxf(mx, __shfl_xor(mx, 8));
    float s = 0.f;
#pragma unroll
    for (int n = 0; n < 4; ++n) {
      const float e = __expf(acc[n][r] - mx);
      acc[n][r] = e;
      s += e;
    }
    s += __shfl_xor(s, 1);
    s += __shfl_xor(s, 2);
    s += __shfl_xor(s, 4);
    s += __shfl_xor(s, 8);
    const float si = 1.0f / s;
#pragma unroll
    for (int n = 0; n < 4; ++n) acc[n][r] *= si;
  }

  // ---- P (normalized, bf16) -> own rows of Plds (same-wave write->read) ----
#pragma unroll
  for (int n = 0; n < 4; ++n)
#pragma unroll
    for (int r = 0; r < 4; ++r)
      Plds[(a0 + r) * PSTR + n * 16 + lr] = f2b(acc[n][r]);

  // ---- PV: A = own P rows (b128), B = V^T rows (swizzled b128) ----
  f32x4 acc2[4] = {};
  const int prow = wv * 16 + lr;
#pragma unroll
  for (int ks = 0; ks < 2; ++ks) {
    bf16x8 pf = *reinterpret_cast<const bf16x8*>(
        &Plds[prow * PSTR + ks * 32 + kg * 8]);
#pragma unroll
    for (int n = 0; n < 4; ++n) {
      const int d = n * 16 + lr;
      bf16x8 vf = *reinterpret_cast<const bf16x8*>(
          &VldsT[d * VTSTR + ((((ks * 4 + kg) ^ (d & 7)) << 3))]);
      acc2[n] = __builtin_amdgcn_mfma_f32_16x16x32_bf16(pf, vf, acc2[n], 0, 0, 0);
    }
  }

  // ---- coalesced O store: O -> LDS (reuse VldsT, now dead) -> 16B chunks ----
  __syncthreads();   // all waves finished PV reads of VldsT
  unsigned short* Olds = VldsT;  // rows a<49 x 64 cols, stride VTSTR (16B-aligned)
#pragma unroll
  for (int r = 0; r < 4; ++r) {
    const int a = a0 + r;
    if (a < NT) {
#pragma unroll
      for (int n = 0; n < 4; ++n)
        Olds[a * VTSTR + n * 16 + lr] = f2b(acc2[n][r]);
    }
  }
  __syncthreads();
  // 392 chunks of 8 bf16: thread t -> row t>>3, cols (t&7)*8 (128B/row lines)
  {
    const int oa0 = tid >> 3, oc0 = (tid & 7) * 8;
    bf16x8 ov0 = *reinterpret_cast<const bf16x8*>(&Olds[oa0 * VTSTR + oc0]);
    *reinterpret_cast<bf16x8*>(
        &aout[((size_t)(w * NT + oa0)) * KDIM + h * HD + oc0]) = ov0;
    const int i2 = tid + 256, oa1 = i2 >> 3, oc1 = (i2 & 7) * 8;
    if (oa1 < NT) {
      bf16x8 ov1 = *reinterpret_cast<const bf16x8*>(&Olds[oa1 * VTSTR + oc1]);
      *reinterpret_cast<bf16x8*>(
          &aout[((size_t)(w * NT + oa1)) * KDIM + h * HD + oc1]) = ov1;
    }
  }
}

extern "C" void kernel_launch(void* const* d_in, const int* in_sizes, int n_in,
                              void* d_out, int out_size, void* d_ws, size_t ws_size,
                              hipStream_t stream) {
  const float* x          = (const float*)d_in[0];
  const float* attn_mask  = (const float*)d_in[1];
  const float* qkv_w      = (const float*)d_in[2];
  const float* qkv_b      = (const float*)d_in[3];
  const float* proj_w     = (const float*)d_in[4];
  const float* proj_b     = (const float*)d_in[5];
  const float* bias_table = (const float*)d_in[6];
  float* out = (float*)d_out;

  char* ws = (char*)d_ws;
  const size_t xbf_bytes = (size_t)MROWS * KDIM * 2;                 // 205.5 MB
  const size_t qkv_bytes = (size_t)2048 * 3 * HEADS * NTOK * 2;      // 616.6 MB
  unsigned short* xbf      = (unsigned short*)ws;
  unsigned short* qkvw_bf  = (unsigned short*)(ws + xbf_bytes);
  unsigned short* projw_bf = qkvw_bf + 3072 * 1024;
  unsigned short* qkvbuf   = (unsigned short*)(ws + xbf_bytes + 8388608);
  float* bm                = (float*)(ws + xbf_bytes + 8388608 + qkv_bytes); // 12.8 MB
  unsigned short* aout     = xbf;  // x_bf16 dead after QKV GEMM; reuse

  build_bm<<<64 * HEADS, 256, 0, stream>>>(attn_mask, bias_table, bm);

  cvt_f32_bf16<<<8192, 256, 0, stream>>>(x, xbf, (long)MROWS * KDIM / 4);
  cvt_f32_bf16<<<3072, 256, 0, stream>>>(qkv_w, qkvw_bf, (long)3072 * 1024 / 4);
  cvt_f32_bf16<<<1024, 256, 0, stream>>>(proj_w, projw_bf, (long)1024 * 1024 / 4);

  // 256x128 tiles: M tiles = 392, N tiles = 24 (QKV) / 8 (proj)
  gemm_bt<0><<<392 * 24, 256, 0, stream>>>(xbf, qkvw_bf, qkv_b, (void*)qkvbuf, 24);

  attn_mfma<<<2048 * HEADS, 256, 0, stream>>>(qkvbuf, bm, aout);

  gemm_bt<1><<<392 * 8, 256, 0, stream>>>(aout, projw_bf, proj_b, (void*)out, 8);
}

// Round 13
// 1293.826 us; speedup vs baseline: 1.0347x; 1.0347x over previous
//
#include <hip/hip_runtime.h>
#include <hip/hip_bf16.h>
#include <cstdint>
#include <cstddef>

#define HEADS 16
#define HD 64
#define NT 49
#define NTOK 3136          // NT*HD
#define MROWS 100352       // 2048*49
#define KDIM 1024

typedef __attribute__((ext_vector_type(4))) float f32x4;
typedef __attribute__((ext_vector_type(8))) short bf16x8;
typedef __attribute__((ext_vector_type(4))) unsigned short u16x4;

__device__ __forceinline__ unsigned short f2b(float f) {
  __hip_bfloat16 h = __float2bfloat16(f);
  return *reinterpret_cast<unsigned short*>(&h);
}
__device__ __forceinline__ float b2f(unsigned short u) {
  union { unsigned int i; float f; } c; c.i = ((unsigned int)u) << 16; return c.f;
}

__device__ __forceinline__ void gload16(const unsigned short* g, void* l) {
  __builtin_amdgcn_global_load_lds(
      (const __attribute__((address_space(1))) void*)g,
      (__attribute__((address_space(3))) void*)l, 16, 0, 0);
}

__device__ __forceinline__ void bar() {
  asm volatile("" ::: "memory");
  __builtin_amdgcn_s_barrier();
  asm volatile("" ::: "memory");
}

// ---------------- fp32 -> bf16 convert ----------------
__global__ void cvt_f32_bf16(const float* __restrict__ s,
                             unsigned short* __restrict__ d, long n4) {
  long stride = (long)gridDim.x * blockDim.x;
  for (long i = blockIdx.x * (long)blockDim.x + threadIdx.x; i < n4; i += stride) {
    f32x4 v = reinterpret_cast<const f32x4*>(s)[i];
    u16x4 o;
    o.x = f2b(v.x); o.y = f2b(v.y); o.z = f2b(v.z); o.w = f2b(v.w);
    reinterpret_cast<u16x4*>(d)[i] = o;
  }
}

// ---------------- fused (window mask + rel-pos bias) logit table ----------------
// BM[wm][h][a][b] for a<49, b<64; b>=49 baked to -1e30. 64*16*49*64*4B = 12.8 MB.
__global__ void build_bm(const float* __restrict__ mask,
                         const float* __restrict__ bias_table,
                         float* __restrict__ bm) {
  const int wm = blockIdx.x >> 4, h = blockIdx.x & 15;
  const float* mrow = mask + (size_t)wm * (NT * NT);
  float* dst = bm + ((size_t)wm * HEADS + h) * (NT * 64);
  for (int idx = threadIdx.x; idx < NT * 64; idx += 256) {
    const int a = idx >> 6, b = idx & 63;
    float v = -1e30f;
    if (b < NT) {
      const int ia = a / 7, ja = a - ia * 7;
      const int ib = b / 7, jb = b - ib * 7;
      v = mrow[a * NT + b] +
          bias_table[((ia - ib + 6) * 13 + (ja - jb + 6)) * HEADS + h];
    }
    dst[idx] = v;
  }
}

// ---------------- bf16 B^T GEMM, 256x128 tile, BK=32, 4-wave (128x64/wave) ----------------
// (round-10 structure — measured best: ~702 us QKV, MfmaUtil ~41)
template<int EPI>
__global__ __launch_bounds__(256, 2)
void gemm_bt(const unsigned short* __restrict__ A,
             const unsigned short* __restrict__ B,
             const float* __restrict__ bias,
             void* __restrict__ Cout,
             const int nTilesN) {
  __shared__ __align__(16) unsigned short lds[2 * 12288]; // 48 KiB

  const int nwg = gridDim.x;
  const int bid = blockIdx.x;
  const int cpx = nwg >> 3;                       // nwg % 8 == 0 (9408 / 3136)
  const int swz = (bid & 7) * cpx + (bid >> 3);   // XCD-contiguous chunks (T1)
  const int mt = swz / nTilesN;
  const int nt = swz - mt * nTilesN;
  const long mBase = (long)mt * 256;
  const int nBase = nt * 128;

  const int tid = threadIdx.x;
  const int lane = tid & 63;
  const int wid = tid >> 6;
  const int wr = wid >> 1;        // 0..1  (M half: 128 rows)
  const int wc = wid & 1;         // 0..1  (N half: 64 cols)
  const int lr = lane & 15;
  const int kg = lane >> 4;       // 0..3

  // staging: thread covers rows (tid>>2)+64s, slot (tid&3); src col pre-swizzled
  const int srow = tid >> 2;                              // 0..63
  const int c8 = (((tid & 3) ^ ((tid >> 3) & 3)) << 3);   // shorts
  const unsigned short* aSrc = A + (size_t)(mBase + srow) * KDIM + c8;
  const unsigned short* bSrc = B + (size_t)(nBase + srow) * KDIM + c8;
  char* ldsB = (char*)lds;

  f32x4 acc[8][4] = {};

  // fragment read offsets (shorts), swizzled: row*32 + (kg ^ ((row>>1)&3))*8
  int aOff[8], bOff[4];
#pragma unroll
  for (int m = 0; m < 8; ++m) {
    const int row = wr * 128 + m * 16 + lr;
    aOff[m] = row * 32 + ((kg ^ ((row >> 1) & 3)) << 3);
  }
#pragma unroll
  for (int n = 0; n < 4; ++n) {
    const int row = wc * 64 + n * 16 + lr;
    bOff[n] = row * 32 + ((kg ^ ((row >> 1) & 3)) << 3);
  }

  // A: 4 segments of 64 rows (16 KB), B: 2 segments (8 KB); 6 gloads/thread
#define STAGE(buf, kt) do {                                         \
    char* dst = ldsB + (buf) * 24576 + tid * 16;                    \
    _Pragma("unroll")                                               \
    for (int s = 0; s < 4; ++s)                                     \
      gload16(aSrc + (size_t)s * 64 * KDIM + (kt) * 32, dst + s * 4096); \
    _Pragma("unroll")                                               \
    for (int s = 0; s < 2; ++s)                                     \
      gload16(bSrc + (size_t)s * 64 * KDIM + (kt) * 32,             \
              dst + 16384 + s * 4096);                              \
  } while (0)

  // prologue: tiles 0 and 1 in flight; wait tile 0 only (6 per tile per thread)
  STAGE(0, 0);
  STAGE(1, 1);
  asm volatile("s_waitcnt vmcnt(6)" ::: "memory");
  __builtin_amdgcn_sched_barrier(0);
  bar();

  for (int kt = 0; kt < KDIM / 32; ++kt) {
    const int cb = kt & 1;
    const unsigned short* As = lds + cb * 12288;
    const unsigned short* Bs = As + 8192;

    bf16x8 af[8], bfv[4];
#pragma unroll
    for (int m = 0; m < 8; ++m)
      af[m] = *reinterpret_cast<const bf16x8*>(As + aOff[m]);
#pragma unroll
    for (int n = 0; n < 4; ++n)
      bfv[n] = *reinterpret_cast<const bf16x8*>(Bs + bOff[n]);

    __builtin_amdgcn_s_setprio(1);
#pragma unroll
    for (int m = 0; m < 8; ++m)
#pragma unroll
      for (int n = 0; n < 4; ++n)
        acc[m][n] = __builtin_amdgcn_mfma_f32_16x16x32_bf16(
            af[m], bfv[n], acc[m][n], 0, 0, 0);
    __builtin_amdgcn_s_setprio(0);
    bar();   // all waves done reading buf[cb]

    if (kt < KDIM / 32 - 2) {
      STAGE(cb, kt + 2);
      asm volatile("s_waitcnt vmcnt(6)" ::: "memory");  // tile kt+1 landed
      __builtin_amdgcn_sched_barrier(0);
      bar();
    } else if (kt == KDIM / 32 - 2) {
      asm volatile("s_waitcnt vmcnt(0)" ::: "memory");  // drain last tile
      __builtin_amdgcn_sched_barrier(0);
      bar();
    }
  }
#undef STAGE

  if (EPI == 0) {
    unsigned short* qkvbuf = (unsigned short*)Cout;
#pragma unroll
    for (int m = 0; m < 8; ++m) {
      const int row0 = wr * 128 + m * 16 + kg * 4;
#pragma unroll
      for (int n = 0; n < 4; ++n) {
        const int col = nBase + wc * 64 + n * 16 + lr;
        const int which = col >> 10;
        const int head = (col >> 6) & 15;
        const int d = col & 63;
        const float bv = bias[col];
#pragma unroll
        for (int r = 0; r < 4; ++r) {
          const int gm = (int)mBase + row0 + r;
          const int w = gm / NT;
          const int t = gm - w * NT;
          float v = acc[m][n][r] + bv;
          if (which == 0) v *= 0.125f;
          qkvbuf[(((size_t)w * 3 + which) * HEADS + head) * NTOK + t * HD + d] =
              f2b(v);
        }
      }
    }
  } else {
    float* out = (float*)Cout;
#pragma unroll
    for (int m = 0; m < 8; ++m) {
      const int row0 = wr * 128 + m * 16 + kg * 4;
#pragma unroll
      for (int n = 0; n < 4; ++n) {
        const int col = nBase + wc * 64 + n * 16 + lr;
        const float bv = bias[col];
#pragma unroll
        for (int r = 0; r < 4; ++r) {
          const int gm = (int)mBase + row0 + r;
          out[(size_t)gm * KDIM + col] = acc[m][n][r] + bv;
        }
      }
    }
  }
}

// ---------------- window attention: 4 waves per (window, head) ----------------
// Round-9 structure + K staged into LDS via REGISTERS (plain bf16x8 load +
// ds_write_b128 — same proven mechanism as the V^T staging; no gload_lds
// uniformity subtleties). K occupies the front 8 KB of Plds (dead until P)
// as [64 rows][8 slots of 16B], rotation-swizzled: LDS[row][p] holds global
// slot (p+row)&7; reader wants slot s -> p=(s-row)&7 (banks rotate per row:
// distinct over lr 0..7, lr+8 aliases 2-way = free). Post-softmax barrier
// protects the P-overwrite of the K region.
#define PSTR 72   // P LDS stride (elements), 16B-aligned rows
#define VTSTR 72  // V^T LDS stride (elements): 8 data slots of 16B + 1 pad

__global__ __launch_bounds__(256, 8)
void attn_mfma(const unsigned short* __restrict__ qkv,
               const float* __restrict__ bm,
               unsigned short* __restrict__ aout) {
  const int blk = blockIdx.x;
  const int w = blk >> 4;
  const int h = blk & 15;
  const int tid = threadIdx.x;
  const int lane = tid & 63;
  const int wv = tid >> 6;        // 0..3: Q-row quarter
  const int lr = lane & 15;
  const int kg = lane >> 4;

  __shared__ __align__(16) unsigned short Plds[64 * PSTR];   // K stage / P
  __shared__ __align__(16) unsigned short VldsT[64 * VTSTR];

  const unsigned short* qp = qkv + (((size_t)w * 3 + 0) * HEADS + h) * NTOK;
  const unsigned short* kp = qp + (size_t)HEADS * NTOK;
  const unsigned short* vp = qp + (size_t)2 * HEADS * NTOK;
  const float* bmrow = bm + (((size_t)(w & 63) * HEADS + h) * (NT * 64));

  // ---- issue V + K global loads FIRST (load-early / write-late) ----
  // chunk c covers (row = c>>3, 16B slot = c&7); 392 chunks, 2 per thread.
  const int t0 = tid >> 3, s0 = tid & 7;                 // chunks 0..255
  const int idx1 = tid + 256;
  const int t1 = idx1 >> 3, s1 = idx1 & 7;               // chunks 256..391

  bf16x8 vreg0 = *reinterpret_cast<const bf16x8*>(vp + t0 * HD + s0 * 8);
  bf16x8 vreg1 = {};
  if (t1 < NT)
    vreg1 = *reinterpret_cast<const bf16x8*>(vp + t1 * HD + s1 * 8);

  // K source slot rotated: LDS[row][p] <- global slot (p+row)&7
  const int kg0 = (s0 + t0) & 7;
  bf16x8 kreg0 = *reinterpret_cast<const bf16x8*>(kp + t0 * HD + kg0 * 8);
  bf16x8 kreg1 = {};
  const int kg1 = (s1 + t1) & 7;
  if (t1 < NT)
    kreg1 = *reinterpret_cast<const bf16x8*>(kp + t1 * HD + kg1 * 8);

  // ---- bm preload (issued next; consumed after sync) ----
  const int a0 = wv * 16 + kg * 4;          // this wave's 4 a-rows start
  f32x4 acc[4];
#pragma unroll
  for (int r = 0; r < 4; ++r) {
    const int a = a0 + r;
    const int ar = (a > 48) ? 48 : a;
#pragma unroll
    for (int n = 0; n < 4; ++n)
      acc[n][r] = bmrow[ar * 64 + n * 16 + lr];
  }

  // ---- K -> LDS (16B ds_writes; waits on kreg only here) ----
  *reinterpret_cast<bf16x8*>(Plds + t0 * 64 + s0 * 8) = kreg0;
  if (t1 < NT)
    *reinterpret_cast<bf16x8*>(Plds + t1 * 64 + s1 * 8) = kreg1;

  // ---- V^T transpose-write into LDS (waits on vreg only here) ----
  {
    const int ts0 = t0 >> 3, t70 = t0 & 7, c0 = s0 * 8;
#pragma unroll
    for (int ii = 0; ii < 8; ++ii) {
      const int d = c0 + ii;
      VldsT[d * VTSTR + (((ts0 ^ (d & 7)) << 3) + t70)] =
          ((const unsigned short*)&vreg0)[ii];
    }
  }
  if (t1 < NT) {
    const int ts1 = t1 >> 3, t71 = t1 & 7, c1 = s1 * 8;
#pragma unroll
    for (int ii = 0; ii < 8; ++ii) {
      const int d = c1 + ii;
      VldsT[d * VTSTR + (((ts1 ^ (d & 7)) << 3) + t71)] =
          ((const unsigned short*)&vreg1)[ii];
    }
  }
  // zero pad cols t=49..63 for all 64 d-rows (swizzled)
#pragma unroll
  for (int i = 0; i < 4; ++i) {
    const int idx = i * 256 + tid;          // 64*15 = 960
    if (idx < 960) {
      const int d = idx / 15, t = 49 + idx - d * 15;
      VldsT[d * VTSTR + ((((t >> 3) ^ (d & 7)) << 3) + (t & 7))] = 0;
    }
  }
  __syncthreads();   // V^T + K visible to all 4 waves

  // ---- QK^T: Q global frag loads; K frags from LDS (rotated b128) ----
  int qrow = wv * 16 + lr; if (qrow > 48) qrow = 48;
#pragma unroll
  for (int ks = 0; ks < 2; ++ks) {
    bf16x8 af = *reinterpret_cast<const bf16x8*>(qp + qrow * HD + ks * 32 + kg * 8);
#pragma unroll
    for (int n = 0; n < 4; ++n) {
      int row = n * 16 + lr; if (row > 48) row = 48;
      const int slot = ((ks * 4 + kg) - row) & 7;
      bf16x8 bfr = *reinterpret_cast<const bf16x8*>(Plds + row * 64 + slot * 8);
      acc[n] = __builtin_amdgcn_mfma_f32_16x16x32_bf16(af, bfr, acc[n], 0, 0, 0);
    }
  }

  // ---- in-register softmax: row a lives in the 16 lanes sharing kg ----
#pragma unroll
  for (int r = 0; r < 4; ++r) {
    float mx = fmaxf(fmaxf(acc[0][r], acc[1][r]),
                     fmaxf(acc[2][r], acc[3][r]));
    mx = fmaxf(mx, __shfl_xor(mx, 1));
    mx = fmaxf(mx, __shfl_xor(mx, 2));
    mx = fmaxf(mx, __shfl_xor(mx, 4));
    mx = fmaxf(mx, __shfl_xor(mx, 8));
    float s = 0.f;
#pragma unroll
    for (int n = 0; n < 4; ++n) {
      const float e = __expf(acc[n][r] - mx);
      acc[n][r] = e;
      s += e;
    }
    s += __shfl_xor(s, 1);
    s += __shfl_xor(s, 2);
    s += __shfl_xor(s, 4);
    s += __shfl_xor(s, 8);
    const float si = 1.0f / s;
#pragma unroll
    for (int n = 0; n < 4; ++n) acc[n][r] *= si;
  }
  __syncthreads();   // all waves done reading K region before P overwrites it

  // ---- P (normalized, bf16) -> own rows of Plds (same-wave write->read) ----
#pragma unroll
  for (int n = 0; n < 4; ++n)
#pragma unroll
    for (int r = 0; r < 4; ++r)
      Plds[(a0 + r) * PSTR + n * 16 + lr] = f2b(acc[n][r]);

  // ---- PV: A = own P rows (b128), B = V^T rows (swizzled b128) ----
  f32x4 acc2[4] = {};
  const int prow = wv * 16 + lr;
#pragma unroll
  for (int ks = 0; ks < 2; ++ks) {
    bf16x8 pf = *reinterpret_cast<const bf16x8*>(
        &Plds[prow * PSTR + ks * 32 + kg * 8]);
#pragma unroll
    for (int n = 0; n < 4; ++n) {
      const int d = n * 16 + lr;
      bf16x8 vf = *reinterpret_cast<const bf16x8*>(
          &VldsT[d * VTSTR + ((((ks * 4 + kg) ^ (d & 7)) << 3))]);
      acc2[n] = __builtin_amdgcn_mfma_f32_16x16x32_bf16(pf, vf, acc2[n], 0, 0, 0);
    }
  }

  // ---- store O rows a<49, bf16 [w*49+a][h*64+d] ----
#pragma unroll
  for (int r = 0; r < 4; ++r) {
    const int a = a0 + r;
    if (a >= NT) continue;
#pragma unroll
    for (int n = 0; n < 4; ++n) {
      const int d = n * 16 + lr;
      aout[((size_t)(w * NT + a)) * KDIM + h * HD + d] = f2b(acc2[n][r]);
    }
  }
}

extern "C" void kernel_launch(void* const* d_in, const int* in_sizes, int n_in,
                              void* d_out, int out_size, void* d_ws, size_t ws_size,
                              hipStream_t stream) {
  const float* x          = (const float*)d_in[0];
  const float* attn_mask  = (const float*)d_in[1];
  const float* qkv_w      = (const float*)d_in[2];
  const float* qkv_b      = (const float*)d_in[3];
  const float* proj_w     = (const float*)d_in[4];
  const float* proj_b     = (const float*)d_in[5];
  const float* bias_table = (const float*)d_in[6];
  float* out = (float*)d_out;

  char* ws = (char*)d_ws;
  const size_t xbf_bytes = (size_t)MROWS * KDIM * 2;                 // 205.5 MB
  const size_t qkv_bytes = (size_t)2048 * 3 * HEADS * NTOK * 2;      // 616.6 MB
  unsigned short* xbf      = (unsigned short*)ws;
  unsigned short* qkvw_bf  = (unsigned short*)(ws + xbf_bytes);
  unsigned short* projw_bf = qkvw_bf + 3072 * 1024;
  unsigned short* qkvbuf   = (unsigned short*)(ws + xbf_bytes + 8388608);
  float* bm                = (float*)(ws + xbf_bytes + 8388608 + qkv_bytes); // 12.8 MB
  unsigned short* aout     = xbf;  // x_bf16 dead after QKV GEMM; reuse

  build_bm<<<64 * HEADS, 256, 0, stream>>>(attn_mask, bias_table, bm);

  cvt_f32_bf16<<<8192, 256, 0, stream>>>(x, xbf, (long)MROWS * KDIM / 4);
  cvt_f32_bf16<<<3072, 256, 0, stream>>>(qkv_w, qkvw_bf, (long)3072 * 1024 / 4);
  cvt_f32_bf16<<<1024, 256, 0, stream>>>(proj_w, projw_bf, (long)1024 * 1024 / 4);

  // 256x128 tiles: M tiles = 392, N tiles = 24 (QKV) / 8 (proj)
  gemm_bt<0><<<392 * 24, 256, 0, stream>>>(xbf, qkvw_bf, qkv_b, (void*)qkvbuf, 24);

  attn_mfma<<<2048 * HEADS, 256, 0, stream>>>(qkvbuf, bm, aout);

  gemm_bt<1><<<392 * 8, 256, 0, stream>>>(aout, projw_bf, proj_b, (void*)out, 8);
}